// Round 2
// baseline (478.190 us; speedup 1.0000x reference)
//
#include <hip/hip_runtime.h>
#include <hip/hip_bf16.h>
#include <stdint.h>

#define NTOK 8192
#define DM   1024
#define DH   2048
#define NE   16

// 256x256 tiles: GEMM1 panels = DH/256 = 8, GEMM2 panels = DM/256 = 4.
#define Q1MAX 128
#define Q2MAX 64
#define GRID1 (8 * Q1MAX)   // 1024
#define GRID2 (8 * Q2MAX)   // 512

typedef float  f32x4  __attribute__((ext_vector_type(4)));
typedef __bf16 bf16x8 __attribute__((ext_vector_type(8)));

__device__ __forceinline__ unsigned short f2bf(float f) {
  union { __bf16 b; unsigned short u; } c; c.b = (__bf16)f; return c.u;
}

__device__ __forceinline__ void glds16(const void* g, void* l) {
  __builtin_amdgcn_global_load_lds(
      (const __attribute__((address_space(1))) void*)g,
      (__attribute__((address_space(3))) void*)l, 16, 0, 0);
}

// ---------------- router: logits, top-2, softmax; also x -> bf16. NO atomics.
__global__ __launch_bounds__(256) void router_kernel(
    const float* __restrict__ x, const float* __restrict__ Wg,
    unsigned short* __restrict__ xb, int* __restrict__ eidx,
    float* __restrict__ ewt)
{
  const int lane = threadIdx.x & 63;
  const int wave = threadIdx.x >> 6;
  const int t = blockIdx.x * 4 + wave;
  const float* xr = x + (size_t)t * DM;

  float4 xv[4];
#pragma unroll
  for (int c = 0; c < 4; ++c)
    xv[c] = *(const float4*)(xr + c * 256 + lane * 4);

  unsigned short* xbr = xb + (size_t)t * DM;
#pragma unroll
  for (int c = 0; c < 4; ++c) {
    ushort4 u;
    u.x = f2bf(xv[c].x); u.y = f2bf(xv[c].y);
    u.z = f2bf(xv[c].z); u.w = f2bf(xv[c].w);
    *(ushort4*)(xbr + c * 256 + lane * 4) = u;
  }

  float acc[NE];
#pragma unroll
  for (int e = 0; e < NE; ++e) acc[e] = 0.f;
#pragma unroll
  for (int e = 0; e < NE; ++e) {
#pragma unroll
    for (int c = 0; c < 4; ++c) {
      float4 wv = *(const float4*)(Wg + e * DM + c * 256 + lane * 4);
      acc[e] += xv[c].x * wv.x + xv[c].y * wv.y + xv[c].z * wv.z + xv[c].w * wv.w;
    }
  }
#pragma unroll
  for (int e = 0; e < NE; ++e) {
    float v = acc[e];
    v += __shfl_xor(v, 1);  v += __shfl_xor(v, 2);  v += __shfl_xor(v, 4);
    v += __shfl_xor(v, 8);  v += __shfl_xor(v, 16); v += __shfl_xor(v, 32);
    acc[e] = v;
  }
  if (lane == 0) {
    float v0 = -1e30f; int i0 = 0;
#pragma unroll
    for (int e = 0; e < NE; ++e) if (acc[e] > v0) { v0 = acc[e]; i0 = e; }
    float v1 = -1e30f; int i1 = 0;
#pragma unroll
    for (int e = 0; e < NE; ++e) if (e != i0 && acc[e] > v1) { v1 = acc[e]; i1 = e; }
    float p = expf(v1 - v0);
    float s = 1.f / (1.f + p);
    eidx[2 * t] = i0; eidx[2 * t + 1] = i1;
    ewt[2 * t] = s;   ewt[2 * t + 1] = p * s;
  }
}

// ---------------- plan: counts, offsets, scatter, XCD-expert-affine queues ---
__global__ __launch_bounds__(1024) void plan_kernel(
    const int* __restrict__ eidx, const float* __restrict__ ewt,
    int* __restrict__ cnt, int* __restrict__ offv,
    int* __restrict__ tok, float* __restrict__ wtl,
    int* __restrict__ wl1, int* __restrict__ wl2)
{
  __shared__ int wcnt[16][NE];
  __shared__ int wbase[16][NE];
  __shared__ int offs[NE];
  __shared__ int s_nmt[NE];
  __shared__ int s_pnmt[NE + 1];
  __shared__ int s_f[2];           // overflow fallback flags

  const int tid  = threadIdx.x;
  const int wave = tid >> 6;
  const int lane = tid & 63;
  const unsigned long long below = (1ull << lane) - 1ull;

  for (int i = tid; i < GRID1; i += 1024) wl1[i] = -1;
  for (int i = tid; i < GRID2; i += 1024) wl2[i] = -1;

  // phase 1: cache pairs; per-wave per-expert counts via ballot
  int   pe[16];
  float pw[16];
  int   count[NE];
#pragma unroll
  for (int e = 0; e < NE; ++e) count[e] = 0;
#pragma unroll
  for (int r = 0; r < 16; ++r) {
    int p = wave * 1024 + r * 64 + lane;
    pe[r] = eidx[p];
    pw[r] = ewt[p];
#pragma unroll
    for (int e = 0; e < NE; ++e) {
      unsigned long long m = __ballot(pe[r] == e);
      count[e] += (int)__popcll(m);
    }
  }
  if (lane == 0) {
#pragma unroll
    for (int e = 0; e < NE; ++e) wcnt[wave][e] = count[e];
  }
  __syncthreads();

  // phase 2: thread 0 serial scan; offsets + tile geometry + overflow check
  if (tid == 0) {
    int s = 0;
    s_pnmt[0] = 0;
    for (int e = 0; e < NE; ++e) {
      offs[e] = s;
      int t = 0;
      for (int w = 0; w < 16; ++w) { wbase[w][e] = t; t += wcnt[w][e]; }
      cnt[e] = t; offv[e] = s; s += t;
      int nmt = (t + 255) >> 8;
      s_nmt[e] = nmt;
      s_pnmt[e + 1] = s_pnmt[e] + nmt;
    }
    offv[NE] = s;
    int f1 = 0, f2 = 0;
    for (int x = 0; x < 8; ++x) {
      int pmt = s_nmt[x] + s_nmt[x + 8];
      if (pmt * 8 > Q1MAX) f1 = 1;
      if (pmt * 4 > Q2MAX) f2 = 1;
    }
    s_f[0] = f1; s_f[1] = f2;
  }
  __syncthreads();

  // phase 2b: parallel worklist fill (closed-form positions)
  {
    const int totmt = s_pnmt[NE];
    const int f1 = s_f[0], f2 = s_f[1];
    const int T1 = totmt * 8;
    for (int i = tid; i < T1; i += 1024) {
      int gmt = i >> 3, p = i & 7;
      int e = 0;
      while (s_pnmt[e + 1] <= gmt) ++e;
      int mt  = gmt - s_pnmt[e];
      int nmt = s_nmt[e];
      int slot;
      if (!f1) {
        int x    = e & 7;
        int base = (e < 8) ? 0 : s_nmt[e - 8] * 8;
        int pos  = base + p * nmt + mt;
        slot = pos * 8 + x;
      } else {
        slot = s_pnmt[e] * 8 + p * nmt + mt;   // global order fallback
      }
      wl1[slot] = (e << 16) | (mt << 8) | p;
    }
    const int T2 = totmt * 4;
    for (int i = tid; i < T2; i += 1024) {
      int gmt = i >> 2, p = i & 3;
      int e = 0;
      while (s_pnmt[e + 1] <= gmt) ++e;
      int mt  = gmt - s_pnmt[e];
      int nmt = s_nmt[e];
      int h0  = (nmt + 1) >> 1;
      int pos_e = (mt < h0) ? (p * h0 + mt)
                            : (h0 * 4 + p * (nmt - h0) + (mt - h0));
      int slot;
      if (!f2) {
        int x    = e & 7;
        int base = (e < 8) ? 0 : s_nmt[e - 8] * 4;
        slot = (base + pos_e) * 8 + x;
      } else {
        slot = s_pnmt[e] * 4 + pos_e;
      }
      wl2[slot] = (e << 16) | (mt << 8) | p;
    }
  }

  // phase 3: rank + scatter tokens (deterministic)
  int run[NE];
#pragma unroll
  for (int e = 0; e < NE; ++e) run[e] = 0;
#pragma unroll
  for (int r = 0; r < 16; ++r) {
    int p = wave * 1024 + r * 64 + lane;
#pragma unroll
    for (int e = 0; e < NE; ++e) {
      unsigned long long m = __ballot(pe[r] == e);
      if (pe[r] == e) {
        int rank = (int)__popcll(m & below);
        int slot = offs[e] + wbase[wave][e] + run[e] + rank;
        tok[slot] = p >> 1;
        wtl[slot] = pw[r];
      }
      run[e] += (int)__popcll(m);
    }
  }
}

// ---------------- weight prep: fp32 [E][K][N] -> bf16 [E][N][K] -------------
__global__ __launch_bounds__(256) void wprep_kernel(
    const float* __restrict__ W, unsigned short* __restrict__ WT,
    int K, int N)
{
  __shared__ float t[64][68];
  const int e = blockIdx.z;
  const int k0 = blockIdx.y * 64;
  const int n0 = blockIdx.x * 64;
  const int tid = threadIdx.x;
  const int tr = tid >> 2;
  const int tc = (tid & 3) * 16;
  const float* src = W + ((size_t)e * K + k0) * N + n0;
#pragma unroll
  for (int j = 0; j < 4; ++j) {
    float4 v = *(const float4*)(src + (size_t)tr * N + tc + j * 4);
    t[tc + j * 4 + 0][tr] = v.x;
    t[tc + j * 4 + 1][tr] = v.y;
    t[tc + j * 4 + 2][tr] = v.z;
    t[tc + j * 4 + 3][tr] = v.w;
  }
  __syncthreads();
  unsigned short* dst = WT + ((size_t)e * N + n0) * K + k0;
#pragma unroll
  for (int j = 0; j < 4; ++j) {
    float4 v = *(const float4*)(&t[tr][tc + j * 4]);
    ushort4 u;
    u.x = f2bf(v.x); u.y = f2bf(v.y); u.z = f2bf(v.z); u.w = f2bf(v.w);
    *(ushort4*)(dst + (size_t)tr * K + tc + j * 4) = u;
  }
}

// ---------------- 256x256 gathered GEMM, 8-phase counted-vmcnt schedule -----
// T3+T4+T5 per m201/m248: K-tile (BK=64) staged as 2 K-halves (32 k) per
// operand; 4 phases/K-tile = (kk, qm); per phase: {4-or-8 ds_read_b128 |
// 2 global_load_lds (one half-tile) | counted vmcnt(4) at half-pair
// boundaries, never 0 in main loop | s_barrier | setprio(1) 16 MFMA
// setprio(0) | s_barrier}.  FIFO proof: at each wait, outstanding = 4
// half-tiles (8 loads); vmcnt(4) retires exactly the 2 halves needed by the
// next 2 phases, leaving 2 in flight across the barrier.
// LDS half-region rows are 64 B; swizzle: phys chunk = q ^ ((row>>1)&3),
// inverse applied on the global source (both-sides-or-neither, rule 21).
// Slot math: 64 lanes -> 8 slots x 2 lanes = 2-way = free.
// EPI=0: h = relu(acc+b1) -> bf16    EPI=1: atomicAdd(out, (acc+b2)*w)
#define BARRIER_() asm volatile("s_barrier" ::: "memory")
#define WAITV4_()  asm volatile("s_waitcnt vmcnt(4)" ::: "memory")
#define WAITV0_()  asm volatile("s_waitcnt vmcnt(0)" ::: "memory")
#define FENCE_()   asm volatile("" ::: "memory")

template<int GATHER, int EPI, int KDIM, int NDIM>
__global__ __launch_bounds__(512, 2) void gemm_kernel(
    const unsigned short* __restrict__ Abase,
    const unsigned short* __restrict__ BT,
    const float* __restrict__ bias,
    const int* __restrict__ cnt, const int* __restrict__ offv,
    const int* __restrict__ tok, const float* __restrict__ wtl,
    const int* __restrict__ wl, void* __restrict__ outp)
{
  const int v = wl[blockIdx.x];
  if (v < 0) return;
  const int e  = (v >> 16) & 0xff;
  const int m0 = ((v >> 8) & 0xff) * 256;
  const int n0 = (v & 0xff) * 256;
  const int count = cnt[e];
  const int o     = offv[e];

  // [dbuf][half][256 rows][32 shorts(=64B)] per operand -> 64 KB each, 128 KB
  __shared__ unsigned short Al[2][2][256 * 32];
  __shared__ unsigned short Bl[2][2][256 * 32];

  const int tid  = threadIdx.x;
  const int lane = tid & 63;
  const int wave = tid >> 6;
  const int wr = wave >> 2;        // 0..1  (M half: 128 rows)
  const int wc = wave & 3;         // 0..3  (N quarter: 64 cols)

  // ---- staging lane decomposition: one glds16 = 16 rows x 64 B (1 KB)
  const int lr5 = lane >> 2;       // 0..15 row within instr
  const int lc2 = lane & 3;        // phys chunk within half
  const int rot = (lr5 >> 1) & 3;
  const int scs = (lc2 ^ rot) * 8; // inverse-swizzled source chunk (shorts)

  const unsigned short* aR[2];
  const unsigned short* bR[2];
#pragma unroll
  for (int j = 0; j < 2; ++j) {
    int r = wave * 32 + j * 16 + lr5;
    int m = m0 + r; if (m > count - 1) m = count - 1;
    size_t arow = GATHER ? (size_t)tok[o + m] : (size_t)(o + m);
    aR[j] = Abase + arow * KDIM + scs;
    bR[j] = BT + ((size_t)e * NDIM + n0 + r) * KDIM + scs;
  }
  const int ldso0 = (wave * 32) * 32;        // LDS short-offset, j=0 rows
  const int ldso1 = (wave * 32 + 16) * 32;   // j=1 rows

#define STAGE_A(db, h, tt) {                                              \
    glds16(aR[0] + (tt) * 64 + (h) * 32, &Al[db][h][ldso0]);              \
    glds16(aR[1] + (tt) * 64 + (h) * 32, &Al[db][h][ldso1]); }
#define STAGE_B(db, h, tt) {                                              \
    glds16(bR[0] + (tt) * 64 + (h) * 32, &Bl[db][h][ldso0]);              \
    glds16(bR[1] + (tt) * 64 + (h) * 32, &Bl[db][h][ldso1]); }

  // ---- ds_read lane mapping (MFMA fragments)
  const int q    = lane >> 4;      // source k-chunk within half
  const int ln15 = lane & 15;
  const int cph  = q ^ ((ln15 >> 1) & 3);            // phys chunk
  const int aoff = (wr * 128 + ln15) * 32 + cph * 8; // + (qm*64+a*16)*32
  const int boff = (wc * 64  + ln15) * 32 + cph * 8; // + b*512

  f32x4 acc[8][4];
#pragma unroll
  for (int a = 0; a < 8; ++a)
#pragma unroll
    for (int b = 0; b < 4; ++b) acc[a][b] = 0.f;

  bf16x8 af[4], bg[4];

  // one phase: reads | issue | (wait) | barrier | prio1 16xMFMA prio0 | barrier
#define PHASE(db, KK, QM, LOADB, PRE_WAIT, ISSUE)                         \
  {                                                                       \
    if (LOADB) {                                                          \
      _Pragma("unroll")                                                   \
      for (int b = 0; b < 4; ++b)                                         \
        bg[b] = *(const bf16x8*)(&Bl[db][KK][boff + b * 512]);            \
    }                                                                     \
    _Pragma("unroll")                                                     \
    for (int a = 0; a < 4; ++a)                                           \
      af[a] = *(const bf16x8*)(&Al[db][KK][aoff + (QM) * 2048 + a * 512]);\
    ISSUE;                                                                \
    PRE_WAIT;                                                             \
    BARRIER_();                                                           \
    __builtin_amdgcn_s_setprio(1);                                        \
    _Pragma("unroll")                                                     \
    for (int a = 0; a < 4; ++a)                                           \
      _Pragma("unroll")                                                   \
      for (int b = 0; b < 4; ++b)                                         \
        acc[(QM) * 4 + a][b] = __builtin_amdgcn_mfma_f32_16x16x32_bf16(   \
            af[a], bg[b], acc[(QM) * 4 + a][b], 0, 0, 0);                 \
    __builtin_amdgcn_s_setprio(0);                                        \
    BARRIER_();                                                           \
  }

  constexpr int NT = KDIM / 64;

  // prologue: issue tile 0's 4 half-tiles IN ORDER (FIFO count relies on it)
  STAGE_A(0, 0, 0); FENCE_();
  STAGE_B(0, 0, 0); FENCE_();
  STAGE_A(0, 1, 0); FENCE_();
  STAGE_B(0, 1, 0); FENCE_();
  WAITV4_();           // retire Ah0,Bh0 of tile 0; Ah1,Bh1 stay in flight
  BARRIER_();

  int db = 0;
  for (int t = 0; t < NT - 1; ++t) {
    const int nx = db ^ 1;
    PHASE(db, 0, 0, 1,          , STAGE_A(nx, 0, t + 1))
    PHASE(db, 0, 1, 0, WAITV4_(), STAGE_B(nx, 0, t + 1))
    PHASE(db, 1, 0, 1,          , STAGE_A(nx, 1, t + 1))
    PHASE(db, 1, 1, 0, WAITV4_(), STAGE_B(nx, 1, t + 1))
    db = nx;
  }
  // peeled last tile: no prefetch; drain remaining half-pair before kk=1
  PHASE(db, 0, 0, 1,          , )
  PHASE(db, 0, 1, 0, WAITV0_(), )
  PHASE(db, 1, 0, 1,          , )
  PHASE(db, 1, 1, 0,          , )

#undef PHASE
#undef STAGE_A
#undef STAGE_B

  float bn[4];
#pragma unroll
  for (int b = 0; b < 4; ++b)
    bn[b] = bias[(size_t)e * NDIM + n0 + wc * 64 + b * 16 + ln15];

  // acc[idx] -> rows wr*128 + (idx>>2)*64 + (idx&3)*16 + q*4 + rg
  if (EPI == 0) {
    unsigned short* hout = (unsigned short*)outp;
#pragma unroll
    for (int idx = 0; idx < 8; ++idx) {
      int rb = wr * 128 + (idx >> 2) * 64 + (idx & 3) * 16;
#pragma unroll
      for (int rg = 0; rg < 4; ++rg) {
        int m = m0 + rb + q * 4 + rg;
        if (m < count) {
          size_t slot = (size_t)(o + m);
#pragma unroll
          for (int b = 0; b < 4; ++b) {
            float v2 = acc[idx][b][rg] + bn[b];
            v2 = v2 > 0.f ? v2 : 0.f;
            hout[slot * NDIM + n0 + wc * 64 + b * 16 + ln15] = f2bf(v2);
          }
        }
      }
    }
  } else {
    float* obase = (float*)outp;
#pragma unroll
    for (int idx = 0; idx < 8; ++idx) {
      int rb = wr * 128 + (idx >> 2) * 64 + (idx & 3) * 16;
#pragma unroll
      for (int rg = 0; rg < 4; ++rg) {
        int m = m0 + rb + q * 4 + rg;
        if (m < count) {
          int slot = o + m;
          int tk = tok[slot];
          float w = wtl[slot];
#pragma unroll
          for (int b = 0; b < 4; ++b) {
            float v2 = (acc[idx][b][rg] + bn[b]) * w;
            atomicAdd(&obase[(size_t)tk * NDIM + n0 + wc * 64 + b * 16 + ln15], v2);
          }
        }
      }
    }
  }
}

// ---------------- launch ----------------------------------------------------
extern "C" void kernel_launch(void* const* d_in, const int* in_sizes, int n_in,
                              void* d_out, int out_size, void* d_ws, size_t ws_size,
                              hipStream_t stream) {
  const float* x  = (const float*)d_in[0];
  const float* Wg = (const float*)d_in[1];
  const float* W1 = (const float*)d_in[2];
  const float* b1 = (const float*)d_in[3];
  const float* W2 = (const float*)d_in[4];
  const float* b2 = (const float*)d_in[5];

  constexpr size_t OFF_CNT  = 0;
  constexpr size_t OFF_OFF  = 256;
  constexpr size_t OFF_WL1  = 4096;
  constexpr size_t OFF_WL2  = OFF_WL1 + (size_t)GRID1 * 4;
  constexpr size_t OFF_EIDX = 131072;
  constexpr size_t OFF_EWT  = OFF_EIDX + (size_t)NTOK * 2 * 4;
  constexpr size_t OFF_TOK  = OFF_EWT  + (size_t)NTOK * 2 * 4;
  constexpr size_t OFF_WTL  = OFF_TOK  + (size_t)NTOK * 2 * 4;
  constexpr size_t OFF_XB   = (size_t)1 << 20;
  constexpr size_t OFF_W1T  = OFF_XB  + (size_t)NTOK * DM * 2;
  constexpr size_t OFF_W2T  = OFF_W1T + (size_t)NE * DM * DH * 2;
  constexpr size_t OFF_H    = OFF_W2T + (size_t)NE * DH * DM * 2;
  constexpr size_t REQ      = OFF_H   + (size_t)NTOK * 2 * DH * 2;

  if (ws_size < REQ) {
    hipMemsetAsync(d_out, 0, (size_t)out_size * 4, stream);
    return;
  }

  char* ws = (char*)d_ws;
  int*   cnt    = (int*)(ws + OFF_CNT);
  int*   offv   = (int*)(ws + OFF_OFF);
  int*   wl1    = (int*)(ws + OFF_WL1);
  int*   wl2    = (int*)(ws + OFF_WL2);
  int*   eidx   = (int*)(ws + OFF_EIDX);
  float* ewt    = (float*)(ws + OFF_EWT);
  int*   tok    = (int*)(ws + OFF_TOK);
  float* wtl    = (float*)(ws + OFF_WTL);
  unsigned short* xb   = (unsigned short*)(ws + OFF_XB);
  unsigned short* w1t  = (unsigned short*)(ws + OFF_W1T);
  unsigned short* w2t  = (unsigned short*)(ws + OFF_W2T);
  unsigned short* hbuf = (unsigned short*)(ws + OFF_H);

  hipMemsetAsync(d_out, 0, (size_t)out_size * 4, stream);   // atomic target

  router_kernel<<<NTOK / 4, 256, 0, stream>>>(x, Wg, xb, eidx, ewt);
  wprep_kernel<<<dim3(DH / 64, DM / 64, NE), 256, 0, stream>>>(W1, w1t, DM, DH);
  wprep_kernel<<<dim3(DM / 64, DH / 64, NE), 256, 0, stream>>>(W2, w2t, DH, DM);
  plan_kernel<<<1, 1024, 0, stream>>>(eidx, ewt, cnt, offv, tok, wtl, wl1, wl2);

  // GEMM1: h = relu(x @ W1 + b1), gathered rows, K=1024, N=2048
  gemm_kernel<1, 0, DM, DH><<<GRID1, 512, 0, stream>>>(
      xb, w1t, b1, cnt, offv, tok, wtl, wl1, hbuf);
  // GEMM2: out[tok] += (h @ W2 + b2) * w, K=2048, N=1024
  gemm_kernel<0, 1, DH, DM><<<GRID2, 512, 0, stream>>>(
      hbuf, w2t, b2, cnt, offv, tok, wtl, wl2, (float*)d_out);
}

// Round 3
// 406.618 us; speedup vs baseline: 1.1760x; 1.1760x over previous
//
#include <hip/hip_runtime.h>
#include <hip/hip_bf16.h>
#include <stdint.h>

#define NTOK 8192
#define DM   1024
#define DH   2048
#define NE   16

// Persistent-worker geometry: 256 CUs x 3 blocks/CU (reg-limited: 96 VGPR +
// 64 AGPR = 160/wave -> 3 waves/SIMD). Per-XCD work queues preserve the
// expert/panel L2 affinity; dynamic stealing kills round-quantization tails.
#define NWRK  768
#define QCAP1 2048   // worst case: one XCD pair owns all 16384 rows -> 128*16
#define QCAP2 1024   // 128 m-tiles * 8 panels

typedef float  f32x4  __attribute__((ext_vector_type(4)));
typedef __bf16 bf16x8 __attribute__((ext_vector_type(8)));

__device__ __forceinline__ unsigned short f2bf(float f) {
  union { __bf16 b; unsigned short u; } c; c.b = (__bf16)f; return c.u;
}

__device__ __forceinline__ void glds16(const void* g, void* l) {
  __builtin_amdgcn_global_load_lds(
      (const __attribute__((address_space(1))) void*)g,
      (__attribute__((address_space(3))) void*)l, 16, 0, 0);
}

// ---------------- router: logits, top-2, softmax; also x -> bf16. NO atomics.
__global__ __launch_bounds__(256) void router_kernel(
    const float* __restrict__ x, const float* __restrict__ Wg,
    unsigned short* __restrict__ xb, int* __restrict__ eidx,
    float* __restrict__ ewt)
{
  const int lane = threadIdx.x & 63;
  const int wave = threadIdx.x >> 6;
  const int t = blockIdx.x * 4 + wave;
  const float* xr = x + (size_t)t * DM;

  float4 xv[4];
#pragma unroll
  for (int c = 0; c < 4; ++c)
    xv[c] = *(const float4*)(xr + c * 256 + lane * 4);

  unsigned short* xbr = xb + (size_t)t * DM;
#pragma unroll
  for (int c = 0; c < 4; ++c) {
    ushort4 u;
    u.x = f2bf(xv[c].x); u.y = f2bf(xv[c].y);
    u.z = f2bf(xv[c].z); u.w = f2bf(xv[c].w);
    *(ushort4*)(xbr + c * 256 + lane * 4) = u;
  }

  float acc[NE];
#pragma unroll
  for (int e = 0; e < NE; ++e) acc[e] = 0.f;
#pragma unroll
  for (int e = 0; e < NE; ++e) {
#pragma unroll
    for (int c = 0; c < 4; ++c) {
      float4 wv = *(const float4*)(Wg + e * DM + c * 256 + lane * 4);
      acc[e] += xv[c].x * wv.x + xv[c].y * wv.y + xv[c].z * wv.z + xv[c].w * wv.w;
    }
  }
#pragma unroll
  for (int e = 0; e < NE; ++e) {
    float v = acc[e];
    v += __shfl_xor(v, 1);  v += __shfl_xor(v, 2);  v += __shfl_xor(v, 4);
    v += __shfl_xor(v, 8);  v += __shfl_xor(v, 16); v += __shfl_xor(v, 32);
    acc[e] = v;
  }
  if (lane == 0) {
    float v0 = -1e30f; int i0 = 0;
#pragma unroll
    for (int e = 0; e < NE; ++e) if (acc[e] > v0) { v0 = acc[e]; i0 = e; }
    float v1 = -1e30f; int i1 = 0;
#pragma unroll
    for (int e = 0; e < NE; ++e) if (e != i0 && acc[e] > v1) { v1 = acc[e]; i1 = e; }
    float p = expf(v1 - v0);
    float s = 1.f / (1.f + p);
    eidx[2 * t] = i0; eidx[2 * t + 1] = i1;
    ewt[2 * t] = s;   ewt[2 * t + 1] = p * s;
  }
}

// ---------------- plan: counts, offsets, scatter, per-XCD contiguous queues -
// XCD x owns experts {x, x+8}. Queue order: expert-outer, panel-outer,
// m-tile-inner (consecutive items share one B panel; A_e stays L2-hot).
// GEMM2 splits each expert's m-range into halves to bound the A slab.
// Queues are dense (0..qn-1); workers fetch via per-XCD atomic counter.
__global__ __launch_bounds__(1024) void plan_kernel(
    const int* __restrict__ eidx, const float* __restrict__ ewt,
    int* __restrict__ cnt, int* __restrict__ offv,
    int* __restrict__ tok, float* __restrict__ wtl,
    int* __restrict__ wl1, int* __restrict__ wl2,
    int* __restrict__ qn1, int* __restrict__ qn2,
    int* __restrict__ qc1, int* __restrict__ qc2)
{
  __shared__ int wcnt[16][NE];
  __shared__ int wbase[16][NE];
  __shared__ int offs[NE];
  __shared__ int s_nmt[NE];
  __shared__ int s_pnmt[NE + 1];

  const int tid  = threadIdx.x;
  const int wave = tid >> 6;
  const int lane = tid & 63;
  const unsigned long long below = (1ull << lane) - 1ull;

  // phase 1: cache pairs; per-wave per-expert counts via ballot
  int   pe[16];
  float pw[16];
  int   count[NE];
#pragma unroll
  for (int e = 0; e < NE; ++e) count[e] = 0;
#pragma unroll
  for (int r = 0; r < 16; ++r) {
    int p = wave * 1024 + r * 64 + lane;
    pe[r] = eidx[p];
    pw[r] = ewt[p];
#pragma unroll
    for (int e = 0; e < NE; ++e) {
      unsigned long long m = __ballot(pe[r] == e);
      count[e] += (int)__popcll(m);
    }
  }
  if (lane == 0) {
#pragma unroll
    for (int e = 0; e < NE; ++e) wcnt[wave][e] = count[e];
  }
  __syncthreads();

  // phase 2: thread 0 serial scan; offsets + tile geometry
  if (tid == 0) {
    int s = 0;
    s_pnmt[0] = 0;
    for (int e = 0; e < NE; ++e) {
      offs[e] = s;
      int t = 0;
      for (int w = 0; w < 16; ++w) { wbase[w][e] = t; t += wcnt[w][e]; }
      cnt[e] = t; offv[e] = s; s += t;
      int nmt = (t + 127) >> 7;
      s_nmt[e] = nmt;
      s_pnmt[e + 1] = s_pnmt[e] + nmt;
    }
    offv[NE] = s;
  }
  __syncthreads();

  // queue sizes + counter reset (one thread per XCD)
  if (tid < 8) {
    qn1[tid] = (s_nmt[tid] + s_nmt[tid + 8]) * 16;
    qn2[tid] = (s_nmt[tid] + s_nmt[tid + 8]) * 8;
    qc1[tid] = 0;
    qc2[tid] = 0;
  }

  // phase 2b: parallel dense queue fill (closed-form positions)
  {
    const int totmt = s_pnmt[NE];
    const int T1 = totmt * 16;
    for (int i = tid; i < T1; i += 1024) {
      int gmt = i >> 4, p = i & 15;
      int e = 0;
      while (s_pnmt[e + 1] <= gmt) ++e;
      int mt  = gmt - s_pnmt[e];
      int nmt = s_nmt[e];
      int x    = e & 7;
      int base = (e < 8) ? 0 : s_nmt[e - 8] * 16;
      wl1[x * QCAP1 + base + p * nmt + mt] = (e << 16) | (mt << 8) | p;
    }
    const int T2 = totmt * 8;
    for (int i = tid; i < T2; i += 1024) {
      int gmt = i >> 3, p = i & 7;
      int e = 0;
      while (s_pnmt[e + 1] <= gmt) ++e;
      int mt  = gmt - s_pnmt[e];
      int nmt = s_nmt[e];
      int h0  = (nmt + 1) >> 1;
      int pos_e = (mt < h0) ? (p * h0 + mt)
                            : (h0 * 8 + p * (nmt - h0) + (mt - h0));
      int x    = e & 7;
      int base = (e < 8) ? 0 : s_nmt[e - 8] * 8;
      wl2[x * QCAP2 + base + pos_e] = (e << 16) | (mt << 8) | p;
    }
  }

  // phase 3: rank + scatter tokens (deterministic)
  int run[NE];
#pragma unroll
  for (int e = 0; e < NE; ++e) run[e] = 0;
#pragma unroll
  for (int r = 0; r < 16; ++r) {
    int p = wave * 1024 + r * 64 + lane;
#pragma unroll
    for (int e = 0; e < NE; ++e) {
      unsigned long long m = __ballot(pe[r] == e);
      if (pe[r] == e) {
        int rank = (int)__popcll(m & below);
        int slot = offs[e] + wbase[wave][e] + run[e] + rank;
        tok[slot] = p >> 1;
        wtl[slot] = pw[r];
      }
      run[e] += (int)__popcll(m);
    }
  }
}

// ---------------- weight prep: fp32 [E][K][N] -> bf16 [E][N][K] -------------
__global__ __launch_bounds__(256) void wprep_kernel(
    const float* __restrict__ W, unsigned short* __restrict__ WT,
    int K, int N)
{
  __shared__ float t[64][68];
  const int e = blockIdx.z;
  const int k0 = blockIdx.y * 64;
  const int n0 = blockIdx.x * 64;
  const int tid = threadIdx.x;
  const int tr = tid >> 2;
  const int tc = (tid & 3) * 16;
  const float* src = W + ((size_t)e * K + k0) * N + n0;
#pragma unroll
  for (int j = 0; j < 4; ++j) {
    float4 v = *(const float4*)(src + (size_t)tr * N + tc + j * 4);
    t[tc + j * 4 + 0][tr] = v.x;
    t[tc + j * 4 + 1][tr] = v.y;
    t[tc + j * 4 + 2][tr] = v.z;
    t[tc + j * 4 + 3][tr] = v.w;
  }
  __syncthreads();
  unsigned short* dst = WT + ((size_t)e * N + n0) * K + k0;
#pragma unroll
  for (int j = 0; j < 4; ++j) {
    float4 v = *(const float4*)(&t[tr][tc + j * 4]);
    ushort4 u;
    u.x = f2bf(v.x); u.y = f2bf(v.y); u.z = f2bf(v.z); u.w = f2bf(v.w);
    *(ushort4*)(dst + (size_t)tr * K + tc + j * 4) = u;
  }
}

// ---------------- 128x128 gathered GEMM, BK=64, m97 2-barrier loop,
// persistent per-XCD work-stealing workers. Inner loop verbatim from the
// verified 164 us/dispatch kernel — only item acquisition changed.
// EPI=0: h = relu(acc+b1) -> bf16    EPI=1: atomicAdd(out, (acc+b2)*w)
template<int GATHER, int EPI, int KDIM, int NDIM, int QCAP>
__global__ __launch_bounds__(256, 3) void gemm_kernel(
    const unsigned short* __restrict__ Abase,
    const unsigned short* __restrict__ BT,
    const float* __restrict__ bias,
    const int* __restrict__ cnt, const int* __restrict__ offv,
    const int* __restrict__ tok, const float* __restrict__ wtl,
    const int* __restrict__ wl, const int* __restrict__ qn,
    int* __restrict__ qc, void* __restrict__ outp)
{
  __shared__ unsigned short Al[128 * 64];
  __shared__ unsigned short Bl[128 * 64];
  __shared__ int s_j;

  const int xcd = blockIdx.x & 7;            // round-robin dispatch -> XCD id
  const int* q_ = wl + xcd * QCAP;
  const int myqn = qn[xcd];

  const int tid  = threadIdx.x;
  const int lane = tid & 63;
  const int wave = tid >> 6;
  const int wr = wave >> 1;
  const int wc = wave & 1;

  const int lr = lane >> 3;
  const int lc = lane & 7;
  const int sc = (lc ^ lr) * 8;        // inverse-swizzled source k-offset
  const int qq   = lane >> 4;
  const int ln15 = lane & 15;
  const int swz  = ln15 & 7;

  for (;;) {
    if (tid == 0) s_j = atomicAdd(&qc[xcd], 1);
    __syncthreads();
    const int j = s_j;
    if (j >= myqn) return;                   // uniform exit
    const int v = q_[j];

    const int e  = (v >> 16) & 0xff;
    const int m0 = ((v >> 8) & 0xff) * 128;
    const int n0 = (v & 0xff) * 128;
    const int count = cnt[e];
    const int o     = offv[e];

    const unsigned short* aptr[4];
    const unsigned short* bptr[4];
#pragma unroll
    for (int ii = 0; ii < 4; ++ii) {
      int i = wave * 4 + ii;
      int r = i * 8 + lr;
      int m = m0 + r; if (m > count - 1) m = count - 1;
      size_t arow = GATHER ? (size_t)tok[o + m] : (size_t)(o + m);
      aptr[ii] = Abase + arow * KDIM + sc;
      bptr[ii] = BT + ((size_t)e * NDIM + n0 + r) * KDIM + sc;
    }

    f32x4 acc[4][4];
#pragma unroll
    for (int a = 0; a < 4; ++a)
#pragma unroll
      for (int b = 0; b < 4; ++b) acc[a][b] = 0.f;

    for (int k0 = 0; k0 < KDIM; k0 += 64) {
#pragma unroll
      for (int ii = 0; ii < 4; ++ii) {
        int i = wave * 4 + ii;
        glds16(aptr[ii] + k0, &Al[i * 512]);
        glds16(bptr[ii] + k0, &Bl[i * 512]);
      }
      __syncthreads();
#pragma unroll
      for (int kk = 0; kk < 2; ++kk) {
        bf16x8 af[4], bg[4];
        const int ch = (kk * 4 + qq) ^ swz;
#pragma unroll
        for (int a = 0; a < 4; ++a) {
          int r = wr * 64 + a * 16 + ln15;
          af[a] = *(const bf16x8*)(&Al[r * 64 + ch * 8]);
        }
#pragma unroll
        for (int b = 0; b < 4; ++b) {
          int r = wc * 64 + b * 16 + ln15;
          bg[b] = *(const bf16x8*)(&Bl[r * 64 + ch * 8]);
        }
#pragma unroll
        for (int a = 0; a < 4; ++a)
#pragma unroll
          for (int b = 0; b < 4; ++b)
            acc[a][b] = __builtin_amdgcn_mfma_f32_16x16x32_bf16(af[a], bg[b], acc[a][b], 0, 0, 0);
      }
      __syncthreads();
    }

    float bn[4];
#pragma unroll
    for (int b = 0; b < 4; ++b)
      bn[b] = bias[(size_t)e * NDIM + n0 + wc * 64 + b * 16 + ln15];

    if (EPI == 0) {
      unsigned short* hout = (unsigned short*)outp;
#pragma unroll
      for (int a = 0; a < 4; ++a)
#pragma unroll
        for (int rg = 0; rg < 4; ++rg) {
          int r = wr * 64 + a * 16 + qq * 4 + rg;
          int m = m0 + r;
          if (m < count) {
            size_t slot = (size_t)(o + m);
#pragma unroll
            for (int b = 0; b < 4; ++b) {
              float v2 = acc[a][b][rg] + bn[b];
              v2 = v2 > 0.f ? v2 : 0.f;
              hout[slot * NDIM + n0 + wc * 64 + b * 16 + ln15] = f2bf(v2);
            }
          }
        }
    } else {
      float* obase = (float*)outp;
#pragma unroll
      for (int a = 0; a < 4; ++a)
#pragma unroll
        for (int rg = 0; rg < 4; ++rg) {
          int r = wr * 64 + a * 16 + qq * 4 + rg;
          int m = m0 + r;
          if (m < count) {
            int slot = o + m;
            int tk = tok[slot];
            float w = wtl[slot];
#pragma unroll
            for (int b = 0; b < 4; ++b) {
              float v2 = (acc[a][b][rg] + bn[b]) * w;
              atomicAdd(&obase[(size_t)tk * NDIM + n0 + wc * 64 + b * 16 + ln15], v2);
            }
          }
        }
    }
    // next item: s_j rewritten only by tid 0 after it re-enters the loop;
    // all other waves have long since read j (K-loop barriers enforce).
  }
}

// ---------------- launch ----------------------------------------------------
extern "C" void kernel_launch(void* const* d_in, const int* in_sizes, int n_in,
                              void* d_out, int out_size, void* d_ws, size_t ws_size,
                              hipStream_t stream) {
  const float* x  = (const float*)d_in[0];
  const float* Wg = (const float*)d_in[1];
  const float* W1 = (const float*)d_in[2];
  const float* b1 = (const float*)d_in[3];
  const float* W2 = (const float*)d_in[4];
  const float* b2 = (const float*)d_in[5];

  constexpr size_t OFF_CNT  = 0;
  constexpr size_t OFF_OFF  = 256;
  constexpr size_t OFF_QN1  = 512;
  constexpr size_t OFF_QN2  = 544;
  constexpr size_t OFF_QC1  = 576;
  constexpr size_t OFF_QC2  = 608;
  constexpr size_t OFF_WL1  = 4096;
  constexpr size_t OFF_WL2  = OFF_WL1 + (size_t)8 * QCAP1 * 4;   // 64 KB
  constexpr size_t OFF_EIDX = 131072;
  constexpr size_t OFF_EWT  = OFF_EIDX + (size_t)NTOK * 2 * 4;
  constexpr size_t OFF_TOK  = OFF_EWT  + (size_t)NTOK * 2 * 4;
  constexpr size_t OFF_WTL  = OFF_TOK  + (size_t)NTOK * 2 * 4;
  constexpr size_t OFF_XB   = (size_t)1 << 20;
  constexpr size_t OFF_W1T  = OFF_XB  + (size_t)NTOK * DM * 2;
  constexpr size_t OFF_W2T  = OFF_W1T + (size_t)NE * DM * DH * 2;
  constexpr size_t OFF_H    = OFF_W2T + (size_t)NE * DH * DM * 2;
  constexpr size_t REQ      = OFF_H   + (size_t)NTOK * 2 * DH * 2;

  if (ws_size < REQ) {
    hipMemsetAsync(d_out, 0, (size_t)out_size * 4, stream);
    return;
  }

  char* ws = (char*)d_ws;
  int*   cnt    = (int*)(ws + OFF_CNT);
  int*   offv   = (int*)(ws + OFF_OFF);
  int*   qn1    = (int*)(ws + OFF_QN1);
  int*   qn2    = (int*)(ws + OFF_QN2);
  int*   qc1    = (int*)(ws + OFF_QC1);
  int*   qc2    = (int*)(ws + OFF_QC2);
  int*   wl1    = (int*)(ws + OFF_WL1);
  int*   wl2    = (int*)(ws + OFF_WL2);
  int*   eidx   = (int*)(ws + OFF_EIDX);
  float* ewt    = (float*)(ws + OFF_EWT);
  int*   tok    = (int*)(ws + OFF_TOK);
  float* wtl    = (float*)(ws + OFF_WTL);
  unsigned short* xb   = (unsigned short*)(ws + OFF_XB);
  unsigned short* w1t  = (unsigned short*)(ws + OFF_W1T);
  unsigned short* w2t  = (unsigned short*)(ws + OFF_W2T);
  unsigned short* hbuf = (unsigned short*)(ws + OFF_H);

  hipMemsetAsync(d_out, 0, (size_t)out_size * 4, stream);   // atomic target

  router_kernel<<<NTOK / 4, 256, 0, stream>>>(x, Wg, xb, eidx, ewt);
  wprep_kernel<<<dim3(DH / 64, DM / 64, NE), 256, 0, stream>>>(W1, w1t, DM, DH);
  wprep_kernel<<<dim3(DM / 64, DH / 64, NE), 256, 0, stream>>>(W2, w2t, DH, DM);
  plan_kernel<<<1, 1024, 0, stream>>>(eidx, ewt, cnt, offv, tok, wtl,
                                      wl1, wl2, qn1, qn2, qc1, qc2);

  // GEMM1: h = relu(x @ W1 + b1), gathered rows, K=1024, N=2048
  gemm_kernel<1, 0, DM, DH, QCAP1><<<NWRK, 256, 0, stream>>>(
      xb, w1t, b1, cnt, offv, tok, wtl, wl1, qn1, qc1, hbuf);
  // GEMM2: out[tok] += (h @ W2 + b2) * w, K=2048, N=1024
  gemm_kernel<0, 1, DH, DM, QCAP2><<<NWRK, 256, 0, stream>>>(
      hbuf, w2t, b2, cnt, offv, tok, wtl, wl2, qn2, qc2, (float*)d_out);
}